// Round 5
// baseline (107.392 us; speedup 1.0000x reference)
//
#include <hip/hip_runtime.h>

#define LOG2PI 1.8378770664093453f

// Shapes: B=128, T=32, DF=256, DZ=128

// ---- reduction helpers ----

__device__ __forceinline__ float waveReduceSum(float v) {
#pragma unroll
    for (int o = 32; o > 0; o >>= 1) v += __shfl_down(v, o, 64);
    return v;
}

// block reduce, returns value to ALL threads; sh must hold blockDim/64 floats
__device__ __forceinline__ float blockReduceSum(float v, float* sh) {
    int lane = threadIdx.x & 63, wid = threadIdx.x >> 6, nw = blockDim.x >> 6;
    v = waveReduceSum(v);
    __syncthreads();
    if (lane == 0) sh[wid] = v;
    __syncthreads();
    float r = sh[0];
    for (int w = 1; w < nw; ++w) r += sh[w];
    return r;
}

// ---- per-HALF float4 reductions for a 256-thread block (halves = waves {0,1} / {2,3}).
__device__ __forceinline__ float4 halfMax4(float4 v, float4* sh) {
#pragma unroll
    for (int o = 32; o > 0; o >>= 1) {
        v.x = fmaxf(v.x, __shfl_down(v.x, o, 64));
        v.y = fmaxf(v.y, __shfl_down(v.y, o, 64));
        v.z = fmaxf(v.z, __shfl_down(v.z, o, 64));
        v.w = fmaxf(v.w, __shfl_down(v.w, o, 64));
    }
    int wid = threadIdx.x >> 6;
    __syncthreads();
    if ((threadIdx.x & 63) == 0) sh[wid] = v;
    __syncthreads();
    int hb = (threadIdx.x >> 7) << 1;
    float4 a = sh[hb], b = sh[hb + 1];
    return make_float4(fmaxf(a.x, b.x), fmaxf(a.y, b.y),
                       fmaxf(a.z, b.z), fmaxf(a.w, b.w));
}

__device__ __forceinline__ float4 halfSum4(float4 v, float4* sh) {
#pragma unroll
    for (int o = 32; o > 0; o >>= 1) {
        v.x += __shfl_down(v.x, o, 64);
        v.y += __shfl_down(v.y, o, 64);
        v.z += __shfl_down(v.z, o, 64);
        v.w += __shfl_down(v.w, o, 64);
    }
    int wid = threadIdx.x >> 6;
    __syncthreads();
    if ((threadIdx.x & 63) == 0) sh[wid] = v;
    __syncthreads();
    int hb = (threadIdx.x >> 7) << 1;
    float4 a = sh[hb], b = sh[hb + 1];
    return make_float4(a.x + b.x, a.y + b.y, a.z + b.z, a.w + b.w);
}

// ---- fused prep: grid 2721 blocks x 256 threads (unchanged from R3/R4 — verified)
#define NB_TZ 512
#define NB_TF 32
#define NB_ZS 2048
#define NB_FS 128

__global__ void prep(const float* __restrict__ zm, const float* __restrict__ zlv,
                     const float* __restrict__ fm, const float* __restrict__ flv,
                     float2* __restrict__ zme, float2* __restrict__ fme,
                     float* __restrict__ cz, float* __restrict__ cf,
                     float* __restrict__ out) {
    __shared__ float S[2 * 32 * 33];
    float (*sm)[33] = (float(*)[33])S;
    float (*se)[33] = (float(*)[33])(S + 32 * 33);
    int blk = blockIdx.x;
    int tid = threadIdx.x;

    if (blk < NB_TZ) {
        // transpose+exp z: blk = t(32) x bt(4) x dt(4)
        int t = blk >> 4, bt = (blk >> 2) & 3, dt = blk & 3;
        int tx = tid & 31, ty = tid >> 5;
        int b0 = bt * 32, d0 = dt * 32;
#pragma unroll
        for (int k = 0; k < 4; ++k) {
            int bl = ty + k * 8;
            int idx = (b0 + bl) * 4096 + t * 128 + d0 + tx;   // coalesced in d
            sm[bl][tx] = zm[idx];
            se[bl][tx] = expf(-2.f * zlv[idx]);
        }
        __syncthreads();
#pragma unroll
        for (int k = 0; k < 4; ++k) {
            int dl = ty + k * 8;
            zme[(t * 128 + d0 + dl) * 128 + b0 + tx] =
                make_float2(sm[tx][dl], se[tx][dl]);          // coalesced in b
        }
    } else if (blk < NB_TZ + NB_TF) {
        // transpose+exp f: blk-512 = bt(4) x dt(8)
        int r = blk - NB_TZ;
        int bt = r >> 3, dt = r & 7;
        int tx = tid & 31, ty = tid >> 5;
        int b0 = bt * 32, d0 = dt * 32;
#pragma unroll
        for (int k = 0; k < 4; ++k) {
            int bl = ty + k * 8;
            int idx = (b0 + bl) * 256 + d0 + tx;
            sm[bl][tx] = fm[idx];
            se[bl][tx] = expf(-2.f * flv[idx]);
        }
        __syncthreads();
#pragma unroll
        for (int k = 0; k < 4; ++k) {
            int dl = ty + k * 8;
            fme[(d0 + dl) * 128 + b0 + tx] = make_float2(sm[tx][dl], se[tx][dl]);
        }
    } else if (blk < NB_TZ + NB_TF + NB_ZS) {
        // z row sums, 2 rows per block; row r: b=r>>5, t=r&31
        int r0 = (blk - NB_TZ - NB_TF) * 2;
        int half = tid >> 7, lane = tid & 127;
        int r = r0 + half;
        int b = r >> 5, t = r & 31;
        float v = 2.f * zlv[b * 4096 + t * 128 + lane];
        v = waveReduceSum(v);
        int wid = tid >> 6;
        if ((tid & 63) == 0) S[wid] = v;
        __syncthreads();
        if (tid == 0)   cz[(r0 & 31) * 128 + (r0 >> 5)] = S[0] + S[1];
        if (tid == 128) { int r1 = r0 + 1; cz[(r1 & 31) * 128 + (r1 >> 5)] = S[2] + S[3]; }
    } else if (blk < NB_TZ + NB_TF + NB_ZS + NB_FS) {
        int b = blk - NB_TZ - NB_TF - NB_ZS;
        float v = 2.f * flv[b * 256 + tid];
        v = blockReduceSum(v, S);
        if (tid == 0) cf[b] = v;
    } else {
        if (tid == 0) out[0] = 0.f;
    }
}

// ---- fully-fused main kernel: grid 512 blocks x 256 threads.
// Block b -> t = (b&7) + 8*(b>>7), i0 = ((b>>3)&15)*8 (i-tile of 8).
// Threads: j = tid&127 (mean index), h = tid>>7 (d-half).
// Computes per (t,i0): z-quadratics (d split 64/64), F rows (d split 128/128),
// lse_f in-block, both LSEs, relu, atomic mean. No F/lse_f round-trip, no fker.
__global__ __launch_bounds__(256) void zker2(
        const float* __restrict__ zs, const float* __restrict__ fs,
        const float2* __restrict__ zme, const float2* __restrict__ fme,
        const float* __restrict__ cz, const float* __restrict__ cf,
        const int* __restrict__ num_train, float* __restrict__ out) {
    __shared__ float s_zs[128 * 8];        // [d][k] z_sample rows, stride 8
    __shared__ float s_fs[256 * 8];        // [d][k] f_sample rows, stride 8
    __shared__ float s_acc[2][8][128];     // [half][k][j], reused z then f
    __shared__ float4 sh4[4];
    int b = blockIdx.x;
    int t = (b & 7) + ((b >> 7) << 3);
    int i0 = ((b >> 3) & 15) * 8;
    int tid = threadIdx.x;
    int j = tid & 127, h = tid >> 7;

    // stage z_sample rows i0..i0+7 (thread (j,h) loads k=h*4..h*4+3 at d=j)
#pragma unroll
    for (int kk = 0; kk < 4; ++kk) {
        int k = h * 4 + kk;
        s_zs[j * 8 + k] = zs[(i0 + k) * 4096 + t * 128 + j];   // coalesced
    }
    // stage f_sample rows i0..i0+7 (tid covers d=0..255 per k)
#pragma unroll
    for (int k = 0; k < 8; ++k)
        s_fs[tid * 8 + k] = fs[(i0 + k) * 256 + tid];          // coalesced
    __syncthreads();

    // ---- z quadratic: half h covers d = h*64 .. h*64+63
    const float2* zp = zme + t * 16384 + h * 64 * 128;
    float accz[8] = {0.f, 0.f, 0.f, 0.f, 0.f, 0.f, 0.f, 0.f};
#pragma unroll 8
    for (int dd = 0; dd < 64; ++dd) {
        float2 me = zp[dd * 128 + j];                  // coalesced, L2-local
        int d = (h << 6) + dd;
        float4 za = *(const float4*)&s_zs[d * 8];      // same-addr broadcast
        float4 zb = *(const float4*)&s_zs[d * 8 + 4];
        float u;
        u = za.x - me.x; accz[0] = fmaf(u * u, me.y, accz[0]);
        u = za.y - me.x; accz[1] = fmaf(u * u, me.y, accz[1]);
        u = za.z - me.x; accz[2] = fmaf(u * u, me.y, accz[2]);
        u = za.w - me.x; accz[3] = fmaf(u * u, me.y, accz[3]);
        u = zb.x - me.x; accz[4] = fmaf(u * u, me.y, accz[4]);
        u = zb.y - me.x; accz[5] = fmaf(u * u, me.y, accz[5]);
        u = zb.z - me.x; accz[6] = fmaf(u * u, me.y, accz[6]);
        u = zb.w - me.x; accz[7] = fmaf(u * u, me.y, accz[7]);
    }

    // ---- f quadratic (F rows recomputed in-block): half h covers d = h*128 .. h*128+127
    const float2* fp = fme + h * 128 * 128;
    float accf[8] = {0.f, 0.f, 0.f, 0.f, 0.f, 0.f, 0.f, 0.f};
#pragma unroll 4
    for (int dd = 0; dd < 128; ++dd) {
        float2 me = fp[dd * 128 + j];                  // coalesced, L2-hot table
        int d = (h << 7) + dd;
        float4 fa = *(const float4*)&s_fs[d * 8];
        float4 fb = *(const float4*)&s_fs[d * 8 + 4];
        float u;
        u = fa.x - me.x; accf[0] = fmaf(u * u, me.y, accf[0]);
        u = fa.y - me.x; accf[1] = fmaf(u * u, me.y, accf[1]);
        u = fa.z - me.x; accf[2] = fmaf(u * u, me.y, accf[2]);
        u = fa.w - me.x; accf[3] = fmaf(u * u, me.y, accf[3]);
        u = fb.x - me.x; accf[4] = fmaf(u * u, me.y, accf[4]);
        u = fb.y - me.x; accf[5] = fmaf(u * u, me.y, accf[5]);
        u = fb.z - me.x; accf[6] = fmaf(u * u, me.y, accf[6]);
        u = fb.w - me.x; accf[7] = fmaf(u * u, me.y, accf[7]);
    }

    // combine z halves
#pragma unroll
    for (int k = 0; k < 8; ++k) s_acc[h][k][j] = accz[k];
    __syncthreads();
    int k0 = h * 4;
    float base = -0.5f * (cz[t * 128 + j] + 128.f * LOG2PI);
    float4 rz;
    rz.x = -0.5f * (s_acc[0][k0 + 0][j] + s_acc[1][k0 + 0][j]) + base;
    rz.y = -0.5f * (s_acc[0][k0 + 1][j] + s_acc[1][k0 + 1][j]) + base;
    rz.z = -0.5f * (s_acc[0][k0 + 2][j] + s_acc[1][k0 + 2][j]) + base;
    rz.w = -0.5f * (s_acc[0][k0 + 3][j] + s_acc[1][k0 + 3][j]) + base;
    __syncthreads();

    // combine f halves -> F rows
#pragma unroll
    for (int k = 0; k < 8; ++k) s_acc[h][k][j] = accf[k];
    __syncthreads();
    float cfb = -0.5f * (cf[j] + 256.f * LOG2PI);
    float4 F4;
    F4.x = -0.5f * (s_acc[0][k0 + 0][j] + s_acc[1][k0 + 0][j]) + cfb;
    F4.y = -0.5f * (s_acc[0][k0 + 1][j] + s_acc[1][k0 + 1][j]) + cfb;
    F4.z = -0.5f * (s_acc[0][k0 + 2][j] + s_acc[1][k0 + 2][j]) + cfb;
    F4.w = -0.5f * (s_acc[0][k0 + 3][j] + s_acc[1][k0 + 3][j]) + cfb;
    float4 fz = make_float4(rz.x + F4.x, rz.y + F4.y, rz.z + F4.z, rz.w + F4.w);

    // three LSEs per half (rows k0..k0+3): z, f, fz
    float4 mz = halfMax4(rz, sh4);
    float4 e = make_float4(expf(rz.x - mz.x), expf(rz.y - mz.y),
                           expf(rz.z - mz.z), expf(rz.w - mz.w));
    float4 sz = halfSum4(e, sh4);
    float4 mF = halfMax4(F4, sh4);
    e = make_float4(expf(F4.x - mF.x), expf(F4.y - mF.y),
                    expf(F4.z - mF.z), expf(F4.w - mF.w));
    float4 sF = halfSum4(e, sh4);
    float4 mf = halfMax4(fz, sh4);
    e = make_float4(expf(fz.x - mf.x), expf(fz.y - mf.y),
                    expf(fz.z - mf.z), expf(fz.w - mf.w));
    float4 sf = halfSum4(e, sh4);

    if (j == 0) {
        float log_norm = logf(128.f * (float)num_train[0]);
        float lz[4]  = {mz.x + logf(sz.x), mz.y + logf(sz.y),
                        mz.z + logf(sz.z), mz.w + logf(sz.w)};
        float lF[4]  = {mF.x + logf(sF.x), mF.y + logf(sF.y),
                        mF.z + logf(sF.z), mF.w + logf(sF.w)};
        float lfz[4] = {mf.x + logf(sf.x), mf.y + logf(sf.y),
                        mf.z + logf(sf.z), mf.w + logf(sf.w)};
        float s = 0.f;
#pragma unroll
        for (int k = 0; k < 4; ++k) {
            float v = lfz[k] - lF[k] - lz[k] + log_norm;
            s += (v > 0.f ? v : 0.f);
        }
        atomicAdd(out, s * (1.f / 4096.f));
    }
}

extern "C" void kernel_launch(void* const* d_in, const int* in_sizes, int n_in,
                              void* d_out, int out_size, void* d_ws, size_t ws_size,
                              hipStream_t stream) {
    const float* f_mean    = (const float*)d_in[0];
    const float* f_logvar  = (const float*)d_in[1];
    const float* f_sample  = (const float*)d_in[2];
    const float* z_mean    = (const float*)d_in[3];
    const float* z_logvar  = (const float*)d_in[4];
    const float* z_sample  = (const float*)d_in[5];
    const int*   num_train = (const int*)d_in[6];
    float* out = (float*)d_out;

    float* ws    = (float*)d_ws;
    float2* zme  = (float2*)ws;              // 524288 float2 (4 MB)
    float2* fme  = (float2*)(ws + 1048576);  // 32768 float2 (256 KB)
    float*  cz   = ws + 1048576 + 65536;     // 4096
    float*  cf   = cz + 4096;                // 128

    prep<<<NB_TZ + NB_TF + NB_ZS + NB_FS + 1, 256, 0, stream>>>(
        z_mean, z_logvar, f_mean, f_logvar, zme, fme, cz, cf, out);
    zker2<<<512, 256, 0, stream>>>(z_sample, f_sample, zme, fme, cz, cf,
                                   num_train, out);
}

// Round 6
// 104.819 us; speedup vs baseline: 1.0246x; 1.0246x over previous
//
#include <hip/hip_runtime.h>

#define LOG2PI 1.8378770664093453f

// Shapes: B=128, T=32, DF=256, DZ=128
//
// Final configuration (best measured: 105.2 us).
// Note: total bench time is dominated by harness-fixed reset work
// (268 MB ws poison fill ~41 us @ ~6.6 TB/s each iteration, input restores,
// graph replay overhead). Our three kernels contribute ~15-20 us; R2-R5
// experiments (dispatch fusion, 2x traffic cut, XCD swizzle, full F-fusion)
// each moved the total by <2%, confirming the harness floor.

// ---- reduction helpers ----

__device__ __forceinline__ float waveReduceSum(float v) {
#pragma unroll
    for (int o = 32; o > 0; o >>= 1) v += __shfl_down(v, o, 64);
    return v;
}

__device__ __forceinline__ float waveReduceMax(float v) {
#pragma unroll
    for (int o = 32; o > 0; o >>= 1) v = fmaxf(v, __shfl_down(v, o, 64));
    return v;
}

// block reduce, returns value to ALL threads; sh must hold blockDim/64 floats
__device__ __forceinline__ float blockReduceSum(float v, float* sh) {
    int lane = threadIdx.x & 63, wid = threadIdx.x >> 6, nw = blockDim.x >> 6;
    v = waveReduceSum(v);
    __syncthreads();
    if (lane == 0) sh[wid] = v;
    __syncthreads();
    float r = sh[0];
    for (int w = 1; w < nw; ++w) r += sh[w];
    return r;
}

__device__ __forceinline__ float blockReduceMax(float v, float* sh) {
    int lane = threadIdx.x & 63, wid = threadIdx.x >> 6, nw = blockDim.x >> 6;
    v = waveReduceMax(v);
    __syncthreads();
    if (lane == 0) sh[wid] = v;
    __syncthreads();
    float r = sh[0];
    for (int w = 1; w < nw; ++w) r = fmaxf(r, sh[w]);
    return r;
}

// ---- per-HALF float4 reductions for a 256-thread block (halves = waves {0,1} / {2,3}).
__device__ __forceinline__ float4 halfMax4(float4 v, float4* sh) {
#pragma unroll
    for (int o = 32; o > 0; o >>= 1) {
        v.x = fmaxf(v.x, __shfl_down(v.x, o, 64));
        v.y = fmaxf(v.y, __shfl_down(v.y, o, 64));
        v.z = fmaxf(v.z, __shfl_down(v.z, o, 64));
        v.w = fmaxf(v.w, __shfl_down(v.w, o, 64));
    }
    int wid = threadIdx.x >> 6;
    __syncthreads();
    if ((threadIdx.x & 63) == 0) sh[wid] = v;
    __syncthreads();
    int hb = (threadIdx.x >> 7) << 1;
    float4 a = sh[hb], b = sh[hb + 1];
    return make_float4(fmaxf(a.x, b.x), fmaxf(a.y, b.y),
                       fmaxf(a.z, b.z), fmaxf(a.w, b.w));
}

__device__ __forceinline__ float4 halfSum4(float4 v, float4* sh) {
#pragma unroll
    for (int o = 32; o > 0; o >>= 1) {
        v.x += __shfl_down(v.x, o, 64);
        v.y += __shfl_down(v.y, o, 64);
        v.z += __shfl_down(v.z, o, 64);
        v.w += __shfl_down(v.w, o, 64);
    }
    int wid = threadIdx.x >> 6;
    __syncthreads();
    if ((threadIdx.x & 63) == 0) sh[wid] = v;
    __syncthreads();
    int hb = (threadIdx.x >> 7) << 1;
    float4 a = sh[hb], b = sh[hb + 1];
    return make_float4(a.x + b.x, a.y + b.y, a.z + b.z, a.w + b.w);
}

// ---- fused prep: grid 2721 blocks x 256 threads
#define NB_TZ 512
#define NB_TF 32
#define NB_ZS 2048
#define NB_FS 128

__global__ void prep(const float* __restrict__ zm, const float* __restrict__ zlv,
                     const float* __restrict__ fm, const float* __restrict__ flv,
                     float2* __restrict__ zme, float2* __restrict__ fme,
                     float* __restrict__ cz, float* __restrict__ cf,
                     float* __restrict__ out) {
    __shared__ float S[2 * 32 * 33];
    float (*sm)[33] = (float(*)[33])S;
    float (*se)[33] = (float(*)[33])(S + 32 * 33);
    int blk = blockIdx.x;
    int tid = threadIdx.x;

    if (blk < NB_TZ) {
        // transpose+exp z: blk = t(32) x bt(4) x dt(4)
        int t = blk >> 4, bt = (blk >> 2) & 3, dt = blk & 3;
        int tx = tid & 31, ty = tid >> 5;
        int b0 = bt * 32, d0 = dt * 32;
#pragma unroll
        for (int k = 0; k < 4; ++k) {
            int bl = ty + k * 8;
            int idx = (b0 + bl) * 4096 + t * 128 + d0 + tx;   // coalesced in d
            sm[bl][tx] = zm[idx];
            se[bl][tx] = expf(-2.f * zlv[idx]);
        }
        __syncthreads();
#pragma unroll
        for (int k = 0; k < 4; ++k) {
            int dl = ty + k * 8;
            zme[(t * 128 + d0 + dl) * 128 + b0 + tx] =
                make_float2(sm[tx][dl], se[tx][dl]);          // coalesced in b
        }
    } else if (blk < NB_TZ + NB_TF) {
        // transpose+exp f: blk-512 = bt(4) x dt(8)
        int r = blk - NB_TZ;
        int bt = r >> 3, dt = r & 7;
        int tx = tid & 31, ty = tid >> 5;
        int b0 = bt * 32, d0 = dt * 32;
#pragma unroll
        for (int k = 0; k < 4; ++k) {
            int bl = ty + k * 8;
            int idx = (b0 + bl) * 256 + d0 + tx;
            sm[bl][tx] = fm[idx];
            se[bl][tx] = expf(-2.f * flv[idx]);
        }
        __syncthreads();
#pragma unroll
        for (int k = 0; k < 4; ++k) {
            int dl = ty + k * 8;
            fme[(d0 + dl) * 128 + b0 + tx] = make_float2(sm[tx][dl], se[tx][dl]);
        }
    } else if (blk < NB_TZ + NB_TF + NB_ZS) {
        // z row sums, 2 rows per block; row r: b=r>>5, t=r&31
        int r0 = (blk - NB_TZ - NB_TF) * 2;
        int half = tid >> 7, lane = tid & 127;
        int r = r0 + half;
        int b = r >> 5, t = r & 31;
        float v = 2.f * zlv[b * 4096 + t * 128 + lane];
        v = waveReduceSum(v);
        int wid = tid >> 6;
        if ((tid & 63) == 0) S[wid] = v;
        __syncthreads();
        if (tid == 0)   cz[(r0 & 31) * 128 + (r0 >> 5)] = S[0] + S[1];
        if (tid == 128) { int r1 = r0 + 1; cz[(r1 & 31) * 128 + (r1 >> 5)] = S[2] + S[3]; }
    } else if (blk < NB_TZ + NB_TF + NB_ZS + NB_FS) {
        int b = blk - NB_TZ - NB_TF - NB_ZS;
        float v = 2.f * flv[b * 256 + tid];
        v = blockReduceSum(v, S);
        if (tid == 0) cf[b] = v;
    } else {
        if (tid == 0) out[0] = 0.f;
    }
}

// ---- F[i,j] + lse_f[i]: grid 128 (i), block 256 = j(128) x dhalf(2)
__global__ void fker(const float* __restrict__ fs, const float2* __restrict__ fme,
                     const float* __restrict__ cf,
                     float* __restrict__ F, float* __restrict__ lse_f) {
    __shared__ float s_fs[256];
    __shared__ float part[256];
    __shared__ float sh[4];
    int i = blockIdx.x, tid = threadIdx.x;
    int j = tid & 127, dh = tid >> 7;
    s_fs[tid] = fs[i * 256 + tid];
    __syncthreads();
    const float2* fp = fme + dh * 128 * 128;
    const float* ss = s_fs + dh * 128;
    float acc = 0.f;
#pragma unroll 8
    for (int d = 0; d < 128; ++d) {
        float2 me = fp[d * 128 + j];      // coalesced
        float df = ss[d] - me.x;          // LDS broadcast
        acc = fmaf(df * df, me.y, acc);
    }
    part[tid] = acc;
    __syncthreads();
    float Fij = 0.f;
    if (dh == 0) {
        Fij = -0.5f * (acc + part[tid + 128] + cf[j] + 256.f * LOG2PI);
        F[i * 128 + j] = Fij;
    }
    float v = (dh == 0) ? Fij : -INFINITY;
    float m = blockReduceMax(v, sh);
    float e = (dh == 0) ? expf(Fij - m) : 0.f;
    float s = blockReduceSum(e, sh);
    if (tid == 0) lse_f[i] = m + logf(s);
}

// ---- hot kernel + fused mean: grid 512 blocks x 256 threads.
// Block b -> t = (b&7) + 8*(b>>7)  [XCD-affine], i0 = ((b>>3)&15)*8 [i-tile of 8].
// Threads: j = tid&127 (mean index), h = tid>>7 (d-half).
__global__ void zker(const float* __restrict__ zs, const float2* __restrict__ zme,
                     const float* __restrict__ cz, const float* __restrict__ F,
                     const float* __restrict__ lse_f, const int* __restrict__ num_train,
                     float* __restrict__ out) {
    __shared__ float s_zs[128 * 8];        // [d][k], stride 8
    __shared__ float s_acc[2][8][128];     // [half][k][j] partial sums
    __shared__ float4 sh4[4];
    int b = blockIdx.x;
    int t = (b & 7) + ((b >> 7) << 3);
    int i0 = ((b >> 3) & 15) * 8;
    int tid = threadIdx.x;
    int j = tid & 127, h = tid >> 7;

#pragma unroll
    for (int kk = 0; kk < 4; ++kk) {
        int k = h * 4 + kk;
        s_zs[j * 8 + k] = zs[(i0 + k) * 4096 + t * 128 + j];   // coalesced
    }
    __syncthreads();

    const float2* zp = zme + t * 16384 + h * 64 * 128;
    float acc[8] = {0.f, 0.f, 0.f, 0.f, 0.f, 0.f, 0.f, 0.f};
#pragma unroll 8
    for (int dd = 0; dd < 64; ++dd) {
        float2 me = zp[dd * 128 + j];                  // coalesced 8B/lane, L2-local
        int d = (h << 6) + dd;
        float4 za = *(const float4*)&s_zs[d * 8];      // LDS same-addr broadcast
        float4 zb = *(const float4*)&s_zs[d * 8 + 4];
        float u;
        u = za.x - me.x; acc[0] = fmaf(u * u, me.y, acc[0]);
        u = za.y - me.x; acc[1] = fmaf(u * u, me.y, acc[1]);
        u = za.z - me.x; acc[2] = fmaf(u * u, me.y, acc[2]);
        u = za.w - me.x; acc[3] = fmaf(u * u, me.y, acc[3]);
        u = zb.x - me.x; acc[4] = fmaf(u * u, me.y, acc[4]);
        u = zb.y - me.x; acc[5] = fmaf(u * u, me.y, acc[5]);
        u = zb.z - me.x; acc[6] = fmaf(u * u, me.y, acc[6]);
        u = zb.w - me.x; acc[7] = fmaf(u * u, me.y, acc[7]);
    }
#pragma unroll
    for (int k = 0; k < 8; ++k) s_acc[h][k][j] = acc[k];
    __syncthreads();

    int k0 = h * 4;
    float base = -0.5f * (cz[t * 128 + j] + 128.f * LOG2PI);
    float4 rz, fz;
    rz.x = -0.5f * (s_acc[0][k0 + 0][j] + s_acc[1][k0 + 0][j]) + base;
    rz.y = -0.5f * (s_acc[0][k0 + 1][j] + s_acc[1][k0 + 1][j]) + base;
    rz.z = -0.5f * (s_acc[0][k0 + 2][j] + s_acc[1][k0 + 2][j]) + base;
    rz.w = -0.5f * (s_acc[0][k0 + 3][j] + s_acc[1][k0 + 3][j]) + base;
    fz.x = rz.x + F[(i0 + k0 + 0) * 128 + j];
    fz.y = rz.y + F[(i0 + k0 + 1) * 128 + j];
    fz.z = rz.z + F[(i0 + k0 + 2) * 128 + j];
    fz.w = rz.w + F[(i0 + k0 + 3) * 128 + j];

    float4 mz = halfMax4(rz, sh4);
    float4 e = make_float4(expf(rz.x - mz.x), expf(rz.y - mz.y),
                           expf(rz.z - mz.z), expf(rz.w - mz.w));
    float4 sz = halfSum4(e, sh4);
    float4 mf = halfMax4(fz, sh4);
    e = make_float4(expf(fz.x - mf.x), expf(fz.y - mf.y),
                    expf(fz.z - mf.z), expf(fz.w - mf.w));
    float4 sf = halfSum4(e, sh4);

    if (j == 0) {
        float log_norm = logf(128.f * (float)num_train[0]);
        float lz[4] = {mz.x + logf(sz.x), mz.y + logf(sz.y),
                       mz.z + logf(sz.z), mz.w + logf(sz.w)};
        float lfz[4] = {mf.x + logf(sf.x), mf.y + logf(sf.y),
                        mf.z + logf(sf.z), mf.w + logf(sf.w)};
        float s = 0.f;
#pragma unroll
        for (int k = 0; k < 4; ++k) {
            float v = lfz[k] - lse_f[i0 + k0 + k] - lz[k] + log_norm;
            s += (v > 0.f ? v : 0.f);
        }
        atomicAdd(out, s * (1.f / 4096.f));
    }
}

extern "C" void kernel_launch(void* const* d_in, const int* in_sizes, int n_in,
                              void* d_out, int out_size, void* d_ws, size_t ws_size,
                              hipStream_t stream) {
    const float* f_mean    = (const float*)d_in[0];
    const float* f_logvar  = (const float*)d_in[1];
    const float* f_sample  = (const float*)d_in[2];
    const float* z_mean    = (const float*)d_in[3];
    const float* z_logvar  = (const float*)d_in[4];
    const float* z_sample  = (const float*)d_in[5];
    const int*   num_train = (const int*)d_in[6];
    float* out = (float*)d_out;

    float* ws    = (float*)d_ws;
    float2* zme  = (float2*)ws;              // 524288 float2 (4 MB)
    float2* fme  = (float2*)(ws + 1048576);  // 32768 float2 (256 KB)
    float*  cz   = ws + 1048576 + 65536;     // 4096
    float*  cf   = cz + 4096;                // 128
    float*  F    = cf + 128;                 // 16384
    float*  lse_f= F + 16384;                // 128

    prep<<<NB_TZ + NB_TF + NB_ZS + NB_FS + 1, 256, 0, stream>>>(
        z_mean, z_logvar, f_mean, f_logvar, zme, fme, cz, cf, out);
    fker<<<128, 256, 0, stream>>>(f_sample, fme, cf, F, lse_f);
    zker<<<512, 256, 0, stream>>>(z_sample, zme, cz, F, lse_f, num_train, out);
}